// Round 13
// baseline (72.703 us; speedup 1.0000x reference)
//
#include <hip/hip_runtime.h>
#include <stdint.h>

typedef unsigned long long u64;
typedef unsigned int u32;
typedef __attribute__((ext_vector_type(8))) short bf16x8;
typedef __attribute__((ext_vector_type(4))) float f32x4;

__device__ __forceinline__ u64 fkey(float f, unsigned idx) {
    unsigned u = __float_as_uint(f);
    u = (u & 0x80000000u) ? ~u : (u | 0x80000000u);
    return ((u64)u << 32) | (u64)idx;
}
__device__ __forceinline__ u64 umin64(u64 a, u64 b) { return a < b ? a : b; }
__device__ __forceinline__ unsigned short f2bf(float f) {   // RNE fp32->bf16
    unsigned u = __float_as_uint(f);
    return (unsigned short)((u + 0x7FFFu + ((u >> 16) & 1u)) >> 16);
}
__device__ __forceinline__ float bf2f(unsigned short b) {
    return __uint_as_float((unsigned)b << 16);
}

// ---------------------------------------------------------------------------
// Kernel 1 (unchanged, proven): split x into bf16 planes, stored LINEAR:
// Xs[row][plane][chunk][col64]; col64 = par*32 + (colin&31),
// colin = (p*48+q)*4 + (j&3), chunk = colin>>5. Granule swizzle applied ONCE,
// by gemm's per-lane global_load_lds source offset (rule 21).
// Also: xsum_lo/hi per row, and global scoreboard init.
// ---------------------------------------------------------------------------
extern "C" __global__ __launch_bounds__(256)
void prep_kernel(const float* __restrict__ x, unsigned short* __restrict__ Xs,
                 float* __restrict__ xsum, u64* __restrict__ sb) {
    __shared__ float xbuf[768];
    const int row = blockIdx.x;          // 0..255
    const int a = row >> 4, i = row & 15;
    for (int pass = 0; pass < 3; ++pass) {
        int t = pass * 256 + threadIdx.x;          // 0..767
        int g = t >> 3, j = t & 7;
        int p = g / 48, q = g - 48 * p;
        float v = x[((size_t)(a * 2 + p) * 126 + (19 + q)) * 128 + (i * 8 + j)];
        xbuf[t] = v;
        unsigned short b1 = f2bf(v);
        unsigned short b2 = f2bf(v - bf2f(b1));
        int par = (j >> 2);                        // 0 = lo, 1 = hi
        int colin = g * 4 + (j & 3);               // 0..383 within parity
        int c = colin >> 5;                        // chunk 0..11
        int col64 = par * 32 + (colin & 31);       // 0..63 within chunk-row
        size_t base = (size_t)row * 1536 + c * 64 + col64;
        Xs[base] = b1;            // plane 0 (x1)
        Xs[base + 768] = b2;      // plane 1 (x2)
    }
    __syncthreads();
    if (threadIdx.x < 2) {
        int off = threadIdx.x ? 4 : 0;
        float s = 0.f;
        for (int g = 0; g < 96; ++g)
            for (int j = 0; j < 4; ++j)
                s += xbuf[g * 8 + off + j];
        xsum[threadIdx.x * 256 + row] = s;
    }
    if (row == 0) {
        for (int t = threadIdx.x; t < 368; t += 256) sb[t] = ~0ULL;
    }
}

// ---------------------------------------------------------------------------
// Kernel 2: r12 structure (best: 63.7us total) + two additive changes:
//   (a) cb(c+1) float4 loads issued AFTER the pre-MFMA barrier (fenced) ->
//       L3 latency ages out under the MFMA phase; split at next chunk top
//       reads ready regs. Registers only -- no LDS hazard, barriers unchanged.
//   (b) s_setprio(1)/(0) around the MFMA cluster (T5: two anti-phased
//       blocks/CU = the proven multi-block regime).
// Block = 64 ent x 256 rows, 512 thr, grid 512, 2 blocks/CU (LDS 80KB).
// 3-product split (x1c1, x2c1, x1c2; validated r11/r12).
// LDS rows 128B of 8 16B granules; logical granule g of row r at g^(r&7).
// Epilogue: exact u64-key argmin -> LDS scoreboard -> 368 global atomicMin.
// ---------------------------------------------------------------------------
extern "C" __global__ __launch_bounds__(512, 4)
void gemm_kernel(const float* __restrict__ cb, const unsigned short* __restrict__ Xs,
                 const float* __restrict__ xsum, u64* __restrict__ sb) {
    __shared__ __align__(16) unsigned short cbt[128][64];   // 16KB
    __shared__ __align__(16) unsigned short xst[512][64];   // 64KB

    const int tid = threadIdx.x;
    const int lane = tid & 63;
    const int wid = tid >> 6;
    const int k0 = blockIdx.x * 64;
    const int eb = (wid & 1) * 32;      // wave entry base (within 64)
    const int rb = (wid >> 1) * 64;     // wave row base
    const int l15 = lane & 15;
    const int g4 = lane >> 4;
    const int h7 = lane & 7;

    // cb staging geometry: e=tid>>4 (0..31), group sgl=(tid>>1)&7, half=tid&1
    const int se = tid >> 4;
    const int sgl = (tid >> 1) & 7;
    const int shalf = tid & 1;
    const int scol = shalf * 32 + sgl * 4;
    const int ssw = (((scol >> 3) ^ (se & 7)) << 3) + (sgl & 1) * 4; // shorts

    // xs source swizzle: source granule = (lane&7) ^ (row&7), row&7 == lane>>3
    const int gswz = h7 ^ (lane >> 3);

    f32x4 acc[2][2][4] = {};            // [parity][m][n]
    float sp0 = 0.f, sq0 = 0.f, sp1 = 0.f, sq1 = 0.f;
    float4 v1, v2;                      // cb regs, prefetched one chunk ahead

    const float* cbbase = cb + (size_t)(k0 + se) * 768 + sgl * 8 + shalf * 4;

    // prologue: load cb(0)
    v1 = *(const float4*)cbbase;
    v2 = *(const float4*)(cbbase + 32 * 768);

    for (int c = 0; c < 12; ++c) {
        __syncthreads();
        // ---- split cb(c) from regs -> swizzled LDS + stats
        {
            sp0 += v1.x + v1.y + v1.z + v1.w;
            sq0 += v1.x * v1.x + v1.y * v1.y + v1.z * v1.z + v1.w * v1.w;
            sp1 += v2.x + v2.y + v2.z + v2.w;
            sq1 += v2.x * v2.x + v2.y * v2.y + v2.z * v2.z + v2.w * v2.w;
            unsigned short a1x = f2bf(v1.x), a1y = f2bf(v1.y), a1z = f2bf(v1.z), a1w = f2bf(v1.w);
            unsigned short a2x = f2bf(v2.x), a2y = f2bf(v2.y), a2z = f2bf(v2.z), a2w = f2bf(v2.w);
            ushort4 c1a = make_ushort4(a1x, a1y, a1z, a1w);
            ushort4 c1b = make_ushort4(f2bf(v1.x - bf2f(a1x)), f2bf(v1.y - bf2f(a1y)),
                                       f2bf(v1.z - bf2f(a1z)), f2bf(v1.w - bf2f(a1w)));
            ushort4 c2a = make_ushort4(a2x, a2y, a2z, a2w);
            ushort4 c2b = make_ushort4(f2bf(v2.x - bf2f(a2x)), f2bf(v2.y - bf2f(a2y)),
                                       f2bf(v2.z - bf2f(a2z)), f2bf(v2.w - bf2f(a2w)));
            *(ushort4*)&cbt[se][ssw]      = c1a;   // rows se..se+96 share se&7
            *(ushort4*)&cbt[se + 64][ssw] = c1b;
            *(ushort4*)&cbt[se + 32][ssw] = c2a;
            *(ushort4*)&cbt[se + 96][ssw] = c2b;
        }
        // ---- stage xs(c): 64KB via global_load_lds (per-lane swizzled source)
#pragma unroll
        for (int i = 0; i < 8; ++i) {
            int row = (wid << 6) + (i << 3) + (lane >> 3);
            const unsigned short* gs = Xs + (size_t)(row & 255) * 1536 + (row >> 8) * 768
                                          + c * 64 + gswz * 8;
            __builtin_amdgcn_global_load_lds(
                (const __attribute__((address_space(1))) u32*)gs,
                (__attribute__((address_space(3))) u32*)&xst[(wid << 6) + (i << 3)][0],
                16, 0, 0);
        }
        __syncthreads();
        // ---- prefetch cb(c+1) into regs: ages out under the MFMA phase
        asm volatile("" ::: "memory");   // keep the loads below the barrier
        if (c < 11) {
            const float* s1 = cbbase + (c + 1) * 64;
            v1 = *(const float4*)s1;
            v2 = *(const float4*)(s1 + 32 * 768);
        }
        // ---- MFMA: per parity: 2m x 4n frags x 3 split products (K=32 each)
        __builtin_amdgcn_s_setprio(1);
#pragma unroll
        for (int par = 0; par < 2; ++par) {
            const int sws = ((((par << 2) | g4) ^ h7) << 3);
            bf16x8 A1[2], A2[2];
#pragma unroll
            for (int m = 0; m < 2; ++m) {
                A1[m] = *(const bf16x8*)&cbt[eb + m * 16 + l15][sws];
                A2[m] = *(const bf16x8*)&cbt[eb + m * 16 + l15 + 64][sws];
            }
#pragma unroll
            for (int n = 0; n < 4; ++n) {
                const unsigned short* xr = &xst[rb + n * 16 + l15][sws];
                bf16x8 B1 = *(const bf16x8*)xr;
                bf16x8 B2 = *(const bf16x8*)(xr + 256 * 64);
#pragma unroll
                for (int m = 0; m < 2; ++m) {
                    acc[par][m][n] = __builtin_amdgcn_mfma_f32_16x16x32_bf16(A1[m], B1, acc[par][m][n], 0, 0, 0);
                    acc[par][m][n] = __builtin_amdgcn_mfma_f32_16x16x32_bf16(A2[m], B1, acc[par][m][n], 0, 0, 0);
                    acc[par][m][n] = __builtin_amdgcn_mfma_f32_16x16x32_bf16(A1[m], B2, acc[par][m][n], 0, 0, 0);
                }
            }
        }
        __builtin_amdgcn_s_setprio(0);
    }

    // ---- finalize stats: reduce over group lanes (masks 2,4,8 keep parity bit0)
#pragma unroll
    for (int m = 2; m <= 8; m <<= 1) {
        sp0 += __shfl_xor(sp0, m); sq0 += __shfl_xor(sq0, m);
        sp1 += __shfl_xor(sp1, m); sq1 += __shfl_xor(sq1, m);
    }
    __syncthreads();                    // all MFMA-phase ds_reads done; cbt dead
    float* stf = (float*)&cbt[0][0];    // [0..63]=csum_lo [64..]=csq_lo [128..]=csum_hi [192..]=csq_hi
    u64* msb = (u64*)((char*)&cbt[0][0] + 1024);   // 368-entry LDS scoreboard
    if ((tid & 15) < 2) {
        int par = tid & 1, e = tid >> 4;
        stf[par * 128 + e]           = sp0;
        stf[par * 128 + 64 + e]      = sq0;
        stf[par * 128 + e + 32]      = sp1;
        stf[par * 128 + 64 + e + 32] = sq1;
    }
    if (tid < 368) msb[tid] = ~0ULL;
    __syncthreads();

    // ---- scoring + argmin: D layout col(N=row)=lane&15, row(M)=(lane>>4)*4+reg
#pragma unroll
    for (int n = 0; n < 4; ++n) {
        const int r = rb + n * 16 + l15;
        const float xl = xsum[r], xh = xsum[256 + r];
        u64 kA = ~0ULL, kB = ~0ULL;
#pragma unroll
        for (int m = 0; m < 2; ++m) {
#pragma unroll
            for (int reg = 0; reg < 4; ++reg) {
                const int el = eb + m * 16 + (g4 << 2) + reg;
                const unsigned kg = (unsigned)(k0 + el);
                float stl = stf[el],       sql = stf[64 + el];
                float sth = stf[128 + el], sqh = stf[192 + el];
                float dl = acc[0][m][n][reg], dh = acc[1][m][n][reg];
                float lo_d = sql - 2.f * dl;
                float lo_m = (384.f - 2.f * stl + sql) - 2.f * (xl - dl);
                float hi_d = sqh - 2.f * dh;
                float hi_m = (384.f - 2.f * sth + sqh) - 2.f * (xh - dh);
                if (l15 < 7) {
                    kA = umin64(kA, umin64(fkey(lo_d, kg), fkey(lo_m, kg + 32768u)));
                    kB = umin64(kB, umin64(fkey(hi_d, kg), fkey(hi_m, kg + 32768u)));
                } else {
                    kA = umin64(kA, umin64(fkey(lo_d + hi_d, kg), fkey(lo_m + hi_m, kg + 32768u)));
                }
            }
        }
        kA = umin64(kA, __shfl_xor(kA, 16));
        kA = umin64(kA, __shfl_xor(kA, 32));
        kB = umin64(kB, __shfl_xor(kB, 16));
        kB = umin64(kB, __shfl_xor(kB, 32));
        if (lane < 16) {
            int a_ = r >> 4;
            if (l15 < 7) {
                atomicMin(&msb[a_ * 23 + l15], kA);
                atomicMin(&msb[a_ * 23 + 7 + l15], kB);
            } else {
                atomicMin(&msb[a_ * 23 + 14 + (l15 - 7)], kA);
            }
        }
    }
    __syncthreads();
    if (tid < 368) atomicMin(&sb[tid], msb[tid]);
}

// ---------------------------------------------------------------------------
// Kernel 3: emit bits. out[a][0:6]=0; bit b: stream s=b/22, bit bb=b%22.
// ---------------------------------------------------------------------------
extern "C" __global__ __launch_bounds__(512)
void bits_kernel(const u64* __restrict__ sb, float* __restrict__ out) {
    const int a = blockIdx.x;
    const int pos = threadIdx.x;   // 0..511
    float v = 0.f;
    if (pos >= 6) {
        int b = pos - 6;
        int s = b / 22;
        int bb = b - s * 22;
        unsigned idx = (unsigned)(sb[a * 23 + s] & 0xFFFFFFFFu);
        v = (float)((idx >> bb) & 1u);
    }
    out[a * 512 + pos] = v;
}

extern "C" void kernel_launch(void* const* d_in, const int* in_sizes, int n_in,
                              void* d_out, int out_size, void* d_ws, size_t ws_size,
                              hipStream_t stream) {
    const float* x  = (const float*)d_in[0];   // [16,2,126,128]
    const float* cb = (const float*)d_in[1];   // [32768,2,48,8]
    char* ws = (char*)d_ws;
    unsigned short* Xs = (unsigned short*)ws;              // 256*1536 bf16 = 768KB
    float* xsum        = (float*)(ws + 786432);            // 512 f32
    u64*   sb          = (u64*)(ws + 788480);              // 368 u64
    float* out = (float*)d_out;

    prep_kernel<<<256, 256, 0, stream>>>(x, Xs, xsum, sb);
    gemm_kernel<<<512, 512, 0, stream>>>(cb, Xs, xsum, sb);
    bits_kernel<<<16, 512, 0, stream>>>(sb, out);
}

// Round 14
// 63.617 us; speedup vs baseline: 1.1428x; 1.1428x over previous
//
#include <hip/hip_runtime.h>
#include <stdint.h>

typedef unsigned long long u64;
typedef unsigned int u32;
typedef __attribute__((ext_vector_type(8))) short bf16x8;
typedef __attribute__((ext_vector_type(4))) float f32x4;

__device__ __forceinline__ u64 fkey(float f, unsigned idx) {
    unsigned u = __float_as_uint(f);
    u = (u & 0x80000000u) ? ~u : (u | 0x80000000u);
    return ((u64)u << 32) | (u64)idx;
}
__device__ __forceinline__ u64 umin64(u64 a, u64 b) { return a < b ? a : b; }
__device__ __forceinline__ unsigned short f2bf(float f) {   // RNE fp32->bf16
    unsigned u = __float_as_uint(f);
    return (unsigned short)((u + 0x7FFFu + ((u >> 16) & 1u)) >> 16);
}
__device__ __forceinline__ float bf2f(unsigned short b) {
    return __uint_as_float((unsigned)b << 16);
}

// ---------------------------------------------------------------------------
// Kernel 1 (unchanged, proven): split x into bf16 planes, stored LINEAR:
// Xs[row][plane][chunk][col64]; col64 = par*32 + (colin&31),
// colin = (p*48+q)*4 + (j&3), chunk = colin>>5. Granule swizzle applied ONCE,
// by gemm's per-lane global_load_lds source offset (rule 21).
// Also: xsum_lo/hi per row, and global scoreboard init.
// ---------------------------------------------------------------------------
extern "C" __global__ __launch_bounds__(256)
void prep_kernel(const float* __restrict__ x, unsigned short* __restrict__ Xs,
                 float* __restrict__ xsum, u64* __restrict__ sb) {
    __shared__ float xbuf[768];
    const int row = blockIdx.x;          // 0..255
    const int a = row >> 4, i = row & 15;
    for (int pass = 0; pass < 3; ++pass) {
        int t = pass * 256 + threadIdx.x;          // 0..767
        int g = t >> 3, j = t & 7;
        int p = g / 48, q = g - 48 * p;
        float v = x[((size_t)(a * 2 + p) * 126 + (19 + q)) * 128 + (i * 8 + j)];
        xbuf[t] = v;
        unsigned short b1 = f2bf(v);
        unsigned short b2 = f2bf(v - bf2f(b1));
        int par = (j >> 2);                        // 0 = lo, 1 = hi
        int colin = g * 4 + (j & 3);               // 0..383 within parity
        int c = colin >> 5;                        // chunk 0..11
        int col64 = par * 32 + (colin & 31);       // 0..63 within chunk-row
        size_t base = (size_t)row * 1536 + c * 64 + col64;
        Xs[base] = b1;            // plane 0 (x1)
        Xs[base + 768] = b2;      // plane 1 (x2)
    }
    __syncthreads();
    if (threadIdx.x < 2) {
        int off = threadIdx.x ? 4 : 0;
        float s = 0.f;
        for (int g = 0; g < 96; ++g)
            for (int j = 0; j < 4; ++j)
                s += xbuf[g * 8 + off + j];
        xsum[threadIdx.x * 256 + row] = s;
    }
    if (row == 0) {
        for (int t = threadIdx.x; t < 368; t += 256) sb[t] = ~0ULL;
    }
}

// ---------------------------------------------------------------------------
// Kernel 2: r12 verbatim -- the measured optimum (63.7us total). Block =
// 64 ent x 256 rows, 512 thr, grid 512, 2 blocks/CU (LDS 80KB). 2-barrier
// chunk loop: stage cb (fp32 read once at chunk top -> covered by the other
// anti-phased block's MFMA; RNE split c1/c2 + fused stats, swizzled ds_write)
// + stage X via global_load_lds (pre-swizzled source) -> barrier -> MFMA
// (3-product split x1c1,x2c1,x1c2; x2c2 dropped, validated r11/r12) -> barrier.
// LDS rows 128B of 8 16B granules; logical granule g of row r at g^(r&7).
// Epilogue: exact u64-key argmin -> LDS scoreboard -> 368 global atomicMin.
// Rejected by measurement: 1-block dbuf (r6), counted-vmcnt (r7), 32x32 tile
// (r9), 4-phase (r10), 3-block split-grid (r11), late cb prefetch + setprio
// (r13, FETCH +11MB).
// ---------------------------------------------------------------------------
extern "C" __global__ __launch_bounds__(512, 4)
void gemm_kernel(const float* __restrict__ cb, const unsigned short* __restrict__ Xs,
                 const float* __restrict__ xsum, u64* __restrict__ sb) {
    __shared__ __align__(16) unsigned short cbt[128][64];   // 16KB
    __shared__ __align__(16) unsigned short xst[512][64];   // 64KB

    const int tid = threadIdx.x;
    const int lane = tid & 63;
    const int wid = tid >> 6;
    const int k0 = blockIdx.x * 64;
    const int eb = (wid & 1) * 32;      // wave entry base (within 64)
    const int rb = (wid >> 1) * 64;     // wave row base
    const int l15 = lane & 15;
    const int g4 = lane >> 4;
    const int h7 = lane & 7;

    // cb staging geometry: e=tid>>4 (0..31), group sgl=(tid>>1)&7, half=tid&1
    const int se = tid >> 4;
    const int sgl = (tid >> 1) & 7;
    const int shalf = tid & 1;
    const int scol = shalf * 32 + sgl * 4;
    const int ssw = (((scol >> 3) ^ (se & 7)) << 3) + (sgl & 1) * 4; // shorts

    // xs source swizzle: source granule = (lane&7) ^ (row&7), row&7 == lane>>3
    const int gswz = h7 ^ (lane >> 3);

    f32x4 acc[2][2][4] = {};            // [parity][m][n]
    float sp0 = 0.f, sq0 = 0.f, sp1 = 0.f, sq1 = 0.f;

    for (int c = 0; c < 12; ++c) {
        __syncthreads();
        // ---- stage cb: 64e x 8 groups x 16B fp32 -> split -> swizzled LDS
        const float* s1 = cb + (size_t)(k0 + se) * 768 + (c * 8 + sgl) * 8 + shalf * 4;
        float4 v1 = *(const float4*)s1;
        float4 v2 = *(const float4*)(s1 + 32 * 768);
        sp0 += v1.x + v1.y + v1.z + v1.w;
        sq0 += v1.x * v1.x + v1.y * v1.y + v1.z * v1.z + v1.w * v1.w;
        sp1 += v2.x + v2.y + v2.z + v2.w;
        sq1 += v2.x * v2.x + v2.y * v2.y + v2.z * v2.z + v2.w * v2.w;
        unsigned short a1x = f2bf(v1.x), a1y = f2bf(v1.y), a1z = f2bf(v1.z), a1w = f2bf(v1.w);
        unsigned short a2x = f2bf(v2.x), a2y = f2bf(v2.y), a2z = f2bf(v2.z), a2w = f2bf(v2.w);
        ushort4 c1a = make_ushort4(a1x, a1y, a1z, a1w);
        ushort4 c1b = make_ushort4(f2bf(v1.x - bf2f(a1x)), f2bf(v1.y - bf2f(a1y)),
                                   f2bf(v1.z - bf2f(a1z)), f2bf(v1.w - bf2f(a1w)));
        ushort4 c2a = make_ushort4(a2x, a2y, a2z, a2w);
        ushort4 c2b = make_ushort4(f2bf(v2.x - bf2f(a2x)), f2bf(v2.y - bf2f(a2y)),
                                   f2bf(v2.z - bf2f(a2z)), f2bf(v2.w - bf2f(a2w)));
        *(ushort4*)&cbt[se][ssw]      = c1a;   // rows se..se+96 share se&7
        *(ushort4*)&cbt[se + 64][ssw] = c1b;
        *(ushort4*)&cbt[se + 32][ssw] = c2a;
        *(ushort4*)&cbt[se + 96][ssw] = c2b;
        // ---- stage xs: 64KB via global_load_lds (per-lane swizzled source)
#pragma unroll
        for (int i = 0; i < 8; ++i) {
            int row = (wid << 6) + (i << 3) + (lane >> 3);
            const unsigned short* gs = Xs + (size_t)(row & 255) * 1536 + (row >> 8) * 768
                                          + c * 64 + gswz * 8;
            __builtin_amdgcn_global_load_lds(
                (const __attribute__((address_space(1))) u32*)gs,
                (__attribute__((address_space(3))) u32*)&xst[(wid << 6) + (i << 3)][0],
                16, 0, 0);
        }
        __syncthreads();
        // ---- MFMA: per parity: 2m x 4n frags x 3 split products (K=32 each)
#pragma unroll
        for (int par = 0; par < 2; ++par) {
            const int sws = ((((par << 2) | g4) ^ h7) << 3);
            bf16x8 A1[2], A2[2];
#pragma unroll
            for (int m = 0; m < 2; ++m) {
                A1[m] = *(const bf16x8*)&cbt[eb + m * 16 + l15][sws];
                A2[m] = *(const bf16x8*)&cbt[eb + m * 16 + l15 + 64][sws];
            }
#pragma unroll
            for (int n = 0; n < 4; ++n) {
                const unsigned short* xr = &xst[rb + n * 16 + l15][sws];
                bf16x8 B1 = *(const bf16x8*)xr;
                bf16x8 B2 = *(const bf16x8*)(xr + 256 * 64);
#pragma unroll
                for (int m = 0; m < 2; ++m) {
                    acc[par][m][n] = __builtin_amdgcn_mfma_f32_16x16x32_bf16(A1[m], B1, acc[par][m][n], 0, 0, 0);
                    acc[par][m][n] = __builtin_amdgcn_mfma_f32_16x16x32_bf16(A2[m], B1, acc[par][m][n], 0, 0, 0);
                    acc[par][m][n] = __builtin_amdgcn_mfma_f32_16x16x32_bf16(A1[m], B2, acc[par][m][n], 0, 0, 0);
                }
            }
        }
    }

    // ---- finalize stats: reduce over group lanes (masks 2,4,8 keep parity bit0)
#pragma unroll
    for (int m = 2; m <= 8; m <<= 1) {
        sp0 += __shfl_xor(sp0, m); sq0 += __shfl_xor(sq0, m);
        sp1 += __shfl_xor(sp1, m); sq1 += __shfl_xor(sq1, m);
    }
    __syncthreads();                    // all MFMA-phase ds_reads done; cbt dead
    float* stf = (float*)&cbt[0][0];    // [0..63]=csum_lo [64..]=csq_lo [128..]=csum_hi [192..]=csq_hi
    u64* msb = (u64*)((char*)&cbt[0][0] + 1024);   // 368-entry LDS scoreboard
    if ((tid & 15) < 2) {
        int par = tid & 1, e = tid >> 4;
        stf[par * 128 + e]           = sp0;
        stf[par * 128 + 64 + e]      = sq0;
        stf[par * 128 + e + 32]      = sp1;
        stf[par * 128 + 64 + e + 32] = sq1;
    }
    if (tid < 368) msb[tid] = ~0ULL;
    __syncthreads();

    // ---- scoring + argmin: D layout col(N=row)=lane&15, row(M)=(lane>>4)*4+reg
#pragma unroll
    for (int n = 0; n < 4; ++n) {
        const int r = rb + n * 16 + l15;
        const float xl = xsum[r], xh = xsum[256 + r];
        u64 kA = ~0ULL, kB = ~0ULL;
#pragma unroll
        for (int m = 0; m < 2; ++m) {
#pragma unroll
            for (int reg = 0; reg < 4; ++reg) {
                const int el = eb + m * 16 + (g4 << 2) + reg;
                const unsigned kg = (unsigned)(k0 + el);
                float stl = stf[el],       sql = stf[64 + el];
                float sth = stf[128 + el], sqh = stf[192 + el];
                float dl = acc[0][m][n][reg], dh = acc[1][m][n][reg];
                float lo_d = sql - 2.f * dl;
                float lo_m = (384.f - 2.f * stl + sql) - 2.f * (xl - dl);
                float hi_d = sqh - 2.f * dh;
                float hi_m = (384.f - 2.f * sth + sqh) - 2.f * (xh - dh);
                if (l15 < 7) {
                    kA = umin64(kA, umin64(fkey(lo_d, kg), fkey(lo_m, kg + 32768u)));
                    kB = umin64(kB, umin64(fkey(hi_d, kg), fkey(hi_m, kg + 32768u)));
                } else {
                    kA = umin64(kA, umin64(fkey(lo_d + hi_d, kg), fkey(lo_m + hi_m, kg + 32768u)));
                }
            }
        }
        kA = umin64(kA, __shfl_xor(kA, 16));
        kA = umin64(kA, __shfl_xor(kA, 32));
        kB = umin64(kB, __shfl_xor(kB, 16));
        kB = umin64(kB, __shfl_xor(kB, 32));
        if (lane < 16) {
            int a_ = r >> 4;
            if (l15 < 7) {
                atomicMin(&msb[a_ * 23 + l15], kA);
                atomicMin(&msb[a_ * 23 + 7 + l15], kB);
            } else {
                atomicMin(&msb[a_ * 23 + 14 + (l15 - 7)], kA);
            }
        }
    }
    __syncthreads();
    if (tid < 368) atomicMin(&sb[tid], msb[tid]);
}

// ---------------------------------------------------------------------------
// Kernel 3: emit bits. out[a][0:6]=0; bit b: stream s=b/22, bit bb=b%22.
// ---------------------------------------------------------------------------
extern "C" __global__ __launch_bounds__(512)
void bits_kernel(const u64* __restrict__ sb, float* __restrict__ out) {
    const int a = blockIdx.x;
    const int pos = threadIdx.x;   // 0..511
    float v = 0.f;
    if (pos >= 6) {
        int b = pos - 6;
        int s = b / 22;
        int bb = b - s * 22;
        unsigned idx = (unsigned)(sb[a * 23 + s] & 0xFFFFFFFFu);
        v = (float)((idx >> bb) & 1u);
    }
    out[a * 512 + pos] = v;
}

extern "C" void kernel_launch(void* const* d_in, const int* in_sizes, int n_in,
                              void* d_out, int out_size, void* d_ws, size_t ws_size,
                              hipStream_t stream) {
    const float* x  = (const float*)d_in[0];   // [16,2,126,128]
    const float* cb = (const float*)d_in[1];   // [32768,2,48,8]
    char* ws = (char*)d_ws;
    unsigned short* Xs = (unsigned short*)ws;              // 256*1536 bf16 = 768KB
    float* xsum        = (float*)(ws + 786432);            // 512 f32
    u64*   sb          = (u64*)(ws + 788480);              // 368 u64
    float* out = (float*)d_out;

    prep_kernel<<<256, 256, 0, stream>>>(x, Xs, xsum, sb);
    gemm_kernel<<<512, 512, 0, stream>>>(cb, Xs, xsum, sb);
    bits_kernel<<<16, 512, 0, stream>>>(sb, out);
}